// Round 1
// 534.771 us; speedup vs baseline: 1.0502x; 1.0502x over previous
//
#include <hip/hip_runtime.h>

typedef __attribute__((ext_vector_type(8))) short short8;
typedef __attribute__((ext_vector_type(4))) float v4f;

#define C_CH 128
#define S_SP 16384
#define NSLICE 16
#define KTOT 384

__device__ inline float bf2f(unsigned short u) {
  union { unsigned int i; float f; } v; v.i = ((unsigned int)u) << 16; return v.f;
}
__device__ inline unsigned short f2bf(float f) {
  union { float f; unsigned int i; } v; v.f = f;
  unsigned int u = v.i;
  return (unsigned short)((u + 0x7FFFu + ((u >> 16) & 1u)) >> 16);
}

__device__ inline void gload_lds16(const unsigned short* g, unsigned short* l) {
  __builtin_amdgcn_global_load_lds(
      (const __attribute__((address_space(1))) void*)g,
      (__attribute__((address_space(3))) void*)l, 16, 0, 0);
}

// ---- weight repack: Wr[o][t*128+c] = bf16(w[o][c][t]); bias fp32 copy --------
__global__ __launch_bounds__(256) void repack_kernel(
    const float* __restrict__ wq, const float* __restrict__ wk,
    const float* __restrict__ wv, const float* __restrict__ wp,
    const float* __restrict__ bq, const float* __restrict__ bk,
    const float* __restrict__ bv, const float* __restrict__ bp,
    unsigned short* __restrict__ Wr, float* __restrict__ biasf)
{
  int i = blockIdx.x * 256 + threadIdx.x;
  const int WN = 4 * 49152;
  if (i < WN) {
    int m = i / 49152;
    int r = i % 49152;
    int o = r / 384, k = r % 384;
    int t = k >> 7, c = k & 127;
    const float* w = (m == 0) ? wq : (m == 1) ? wk : (m == 2) ? wv : wp;
    Wr[i] = f2bf(w[o * 384 + c * 3 + t]);
  } else if (i < WN + 512) {
    int j = i - WN;
    int m = j >> 7, o = j & 127;
    const float* bb = (m == 0) ? bq : (m == 1) ? bk : (m == 2) ? bv : bp;
    biasf[j] = bb[o];
  }
}

// ---- ingress: fp32 [R][C] -> bf16 [C][R], per z-slice (R=128, C=16384) -------
__global__ __launch_bounds__(256) void transpose_f2b_kernel(
    const float* __restrict__ in, unsigned short* __restrict__ out,
    int R, int C)
{
  __shared__ unsigned short t[64][72];
  int tid = threadIdx.x;
  size_t slice = blockIdx.z;
  const float* ip = in + slice * (size_t)R * C;
  unsigned short* op = out + slice * (size_t)R * C;
  int c0 = blockIdx.x * 64, r0 = blockIdx.y * 64;
#pragma unroll
  for (int p = 0; p < 4; ++p) {
    int id = tid + p * 256;
    int row = id >> 4, col = (id & 15) * 4;
    float4 v = *(const float4*)(ip + (size_t)(r0 + row) * C + c0 + col);
    t[row][col + 0] = f2bf(v.x);
    t[row][col + 1] = f2bf(v.y);
    t[row][col + 2] = f2bf(v.z);
    t[row][col + 3] = f2bf(v.w);
  }
  __syncthreads();
#pragma unroll
  for (int p = 0; p < 2; ++p) {
    int id = tid + p * 256;
    int crow = id >> 3, rcol = (id & 7) * 8;
    uint4 v;
    v.x = (unsigned)t[rcol + 0][crow] | ((unsigned)t[rcol + 1][crow] << 16);
    v.y = (unsigned)t[rcol + 2][crow] | ((unsigned)t[rcol + 3][crow] << 16);
    v.z = (unsigned)t[rcol + 4][crow] | ((unsigned)t[rcol + 5][crow] << 16);
    v.w = (unsigned)t[rcol + 6][crow] | ((unsigned)t[rcol + 7][crow] << 16);
    *(uint4*)(op + (size_t)(c0 + crow) * R + r0 + rcol) = v;
  }
}

// ---- egress: bf16 [R][C] -> fp32 [C][R], per z-slice (R=16384, C=128) --------
__global__ __launch_bounds__(256) void transpose_b2f_kernel(
    const unsigned short* __restrict__ in, float* __restrict__ out,
    int R, int C)
{
  __shared__ unsigned short t[64][72];
  int tid = threadIdx.x;
  size_t slice = blockIdx.z;
  const unsigned short* ip = in + slice * (size_t)R * C;
  float* op = out + slice * (size_t)R * C;
  int c0 = blockIdx.x * 64, r0 = blockIdx.y * 64;
#pragma unroll
  for (int p = 0; p < 2; ++p) {
    int id = tid + p * 256;
    int row = id >> 3, col = (id & 7) * 8;
    uint4 v = *(const uint4*)(ip + (size_t)(r0 + row) * C + c0 + col);
    *(uint4*)(&t[row][col]) = v;
  }
  __syncthreads();
#pragma unroll
  for (int p = 0; p < 4; ++p) {
    int id = tid + p * 256;
    int crow = id >> 4, rcol = (id & 15) * 4;
    float4 v;
    v.x = bf2f(t[rcol + 0][crow]);
    v.y = bf2f(t[rcol + 1][crow]);
    v.z = bf2f(t[rcol + 2][crow]);
    v.w = bf2f(t[rcol + 3][crow]);
    *(float4*)(op + (size_t)(c0 + crow) * R + r0 + rcol) = v;
  }
}

// ---- MFMA conv v2: A(weights) persistent in registers, B double-buffered -----
// out[slice][s][o] = bias[o] + sum_k Wr[o,k]*Xc[s,k]
// Per block: M=128 (full o), N=128 spatial, K=384 in up-to-6 phases of 64.
// Wave w owns o-strip [w*32, w*32+32): af[2][12] fragments loaded once.
// B tile [128 s][64 k] bf16, linear LDS via global_load_lds (width 16),
// XOR-swizzled source chunks (rule #21: swizzle source AND read, dest linear).
// Invalid conv taps (zero pad in L) skip phase entirely (A*0 == exact no-op).
__global__ __launch_bounds__(256) void conv_mfma_kernel(
    const unsigned short* __restrict__ inT,
    const unsigned short* __restrict__ Wr_all,
    const float* __restrict__ bias_all,
    unsigned short* __restrict__ outT_all)
{
  __shared__ unsigned short Blds[2][128 * 64];  // 2 x 16 KB, linear (swizzled)

  int z = blockIdx.z;
  const unsigned short* Wr = Wr_all + (size_t)z * 49152;
  const float* bias = bias_all + z * 128;
  unsigned short* outT = outT_all + (size_t)z * NSLICE * S_SP * C_CH;

  int tid = threadIdx.x;
  int s0 = blockIdx.x * 128;
  int slice = blockIdx.y;
  int b = slice >> 3, l = slice & 7;
  int lh = l & 3;
  int t_lo = (lh == 0) ? 1 : 0;          // valid tap range: lp stays in-half
  int t_hi = (lh == 3) ? 1 : 2;
  int ap_hi = t_hi * 2 + 1;              // absolute phases ap = t*2+sub, valid
                                         // range [t_lo*2, ap_hi] is contiguous
                                         // and starts even -> buffer = ap&1

  int w = tid >> 6, lane = tid & 63;
  int quad = lane >> 4, l15 = lane & 15;

  // ---- A fragments, loaded once (L2-resident weights). af[i][ksg]: ----------
  // o-row = w*32 + i*16 + l15, k = ksg*32 + quad*8 .. +7
  short8 af[2][12];
#pragma unroll
  for (int i = 0; i < 2; ++i)
#pragma unroll
    for (int k = 0; k < 12; ++k)
      af[i][k] = *(const short8*)(Wr + (w * 32 + i * 16 + l15) * KTOT + k * 32 + quad * 8);

  v4f acc[2][8];
#pragma unroll
  for (int i = 0; i < 2; ++i)
#pragma unroll
    for (int j = 0; j < 8; ++j)
      acc[i][j] = (v4f){0.f, 0.f, 0.f, 0.f};

  // ---- staging lane geometry (global_load_lds: dest = base + lane*16) -------
  int srow_i = lane >> 3;                 // row within 8-row group
  int scs = (lane & 7) ^ srow_i;          // inverse-swizzled source chunk

  auto STAGE = [&](int t, int sub, int bsel) {
    int lp = l - 1 + t;                   // guaranteed in-half for valid t
    const unsigned short* gb =
        inT + ((size_t)(b * 8 + lp) * S_SP + s0) * C_CH + sub * 64;
#pragma unroll
    for (int q = 0; q < 4; ++q) {
      int row = (w * 4 + q) * 8 + srow_i;
      gload_lds16(gb + (size_t)row * C_CH + scs * 8,
                  &Blds[bsel][(w * 4 + q) * 512]);
    }
  };

  // prologue: stage first valid phase into buffer 0
  STAGE(t_lo, 0, 0);
  asm volatile("s_waitcnt vmcnt(0)" ::: "memory");
  __builtin_amdgcn_s_barrier();

#pragma unroll
  for (int ap = 0; ap < 6; ++ap) {
    int t = ap >> 1, sub = ap & 1;
    if (t < t_lo || t > t_hi) continue;   // block-uniform skip, no barrier

    // issue next phase's stage into the other buffer (one phase ahead)
    if (ap + 1 <= ap_hi)
      STAGE((ap + 1) >> 1, (ap + 1) & 1, (ap + 1) & 1);

    const unsigned short* Bp = &Blds[ap & 1][0];
#pragma unroll
    for (int ks = 0; ks < 2; ++ks) {
      short8 bfr[8];
#pragma unroll
      for (int j = 0; j < 8; ++j) {
        int srow = j * 16 + l15;
        int cs = (ks * 4 + quad) ^ (l15 & 7);   // swizzled read chunk
        bfr[j] = *(const short8*)(Bp + srow * 64 + cs * 8);
      }
#pragma unroll
      for (int i = 0; i < 2; ++i)
#pragma unroll
        for (int j = 0; j < 8; ++j)
          acc[i][j] = __builtin_amdgcn_mfma_f32_16x16x32_bf16(
              af[i][t * 4 + sub * 2 + ks], bfr[j], acc[i][j], 0, 0, 0);
    }
    asm volatile("s_waitcnt vmcnt(0)" ::: "memory");
    __builtin_amdgcn_s_barrier();
  }

  // ---- epilogue: bias + bf16 pack + store -----------------------------------
#pragma unroll
  for (int i = 0; i < 2; ++i) {
    int obase = w * 32 + i * 16 + quad * 4;
    float4 bb = *(const float4*)(bias + obase);
#pragma unroll
    for (int j = 0; j < 8; ++j) {
      int s = s0 + j * 16 + l15;
      float f0 = acc[i][j].x + bb.x;
      float f1 = acc[i][j].y + bb.y;
      float f2 = acc[i][j].z + bb.z;
      float f3 = acc[i][j].w + bb.w;
      uint2 st;
      st.x = (unsigned)f2bf(f0) | ((unsigned)f2bf(f1) << 16);
      st.y = (unsigned)f2bf(f2) | ((unsigned)f2bf(f3) << 16);
      *(uint2*)(outT + ((size_t)slice * S_SP + s) * C_CH + obase) = st;
    }
  }
}

// ---- fused both-direction window attention -----------------------------------
__device__ inline void load16(const unsigned short* p, float* f) {
  uint4 a = *(const uint4*)p;
  uint4 c = *(const uint4*)(p + 8);
  unsigned v[8] = {a.x, a.y, a.z, a.w, c.x, c.y, c.z, c.w};
#pragma unroll
  for (int i = 0; i < 8; ++i) {
    f[2 * i] = bf2f((unsigned short)(v[i] & 0xffffu));
    f[2 * i + 1] = bf2f((unsigned short)(v[i] >> 16));
  }
}

__global__ __launch_bounds__(256) void attn_kernel(
    const unsigned short* __restrict__ QT,
    const unsigned short* __restrict__ KT,
    const unsigned short* __restrict__ VT,
    unsigned short* __restrict__ YT)
{
  int tid = threadIdx.x;
  int wave = tid >> 6, lane = tid & 63;
  int dir = wave & 1;
  int win = blockIdx.x * 2 + (wave >> 1);
  int by = blockIdx.y;
  int b = by >> 2, l0 = by & 3;
  int head = lane >> 3, qi = lane & 7;
  int d0 = win >> 8, h0 = (win >> 4) & 15, w0 = win & 15;
  int lq = l0 + dir * 4;
  int lk = l0 + 4 - dir * 4;
  int sE[8];
#pragma unroll
  for (int e = 0; e < 8; ++e)
    sE[e] = (2 * d0 + (e >> 2)) * 1024 + (2 * h0 + ((e >> 1) & 1)) * 32 + (2 * w0 + (e & 1));

  size_t qbase = ((size_t)(b * 8 + lq) * S_SP + sE[qi]) * C_CH + head * 16;
  size_t kslice = (size_t)(b * 8 + lk) * S_SP;
  float q[16];
  load16(QT + qbase, q);

  float lg[8];
#pragma unroll
  for (int j = 0; j < 8; ++j) {
    float kk[16];
    load16(KT + (kslice + sE[j]) * C_CH + head * 16, kk);
    float d = 0.f;
#pragma unroll
    for (int x = 0; x < 16; ++x) d += q[x] * kk[x];
    lg[j] = d * 0.25f;  // scale = (C/NH)^-0.5 = 1/4
  }
  float m = lg[0];
#pragma unroll
  for (int j = 1; j < 8; ++j) m = fmaxf(m, lg[j]);
  float p[8], sum = 0.f;
#pragma unroll
  for (int j = 0; j < 8; ++j) { p[j] = __expf(lg[j] - m); sum += p[j]; }
  float inv = 1.0f / sum;

  float y[16];
#pragma unroll
  for (int x = 0; x < 16; ++x) y[x] = 0.f;
#pragma unroll
  for (int j = 0; j < 8; ++j) {
    float vv[16];
    load16(VT + (kslice + sE[j]) * C_CH + head * 16, vv);
    float pj = p[j] * inv;
#pragma unroll
    for (int x = 0; x < 16; ++x) y[x] += pj * vv[x];
  }
  uint4 o0, o1;
  o0.x = (unsigned)f2bf(y[0]) | ((unsigned)f2bf(y[1]) << 16);
  o0.y = (unsigned)f2bf(y[2]) | ((unsigned)f2bf(y[3]) << 16);
  o0.z = (unsigned)f2bf(y[4]) | ((unsigned)f2bf(y[5]) << 16);
  o0.w = (unsigned)f2bf(y[6]) | ((unsigned)f2bf(y[7]) << 16);
  o1.x = (unsigned)f2bf(y[8]) | ((unsigned)f2bf(y[9]) << 16);
  o1.y = (unsigned)f2bf(y[10]) | ((unsigned)f2bf(y[11]) << 16);
  o1.z = (unsigned)f2bf(y[12]) | ((unsigned)f2bf(y[13]) << 16);
  o1.w = (unsigned)f2bf(y[14]) | ((unsigned)f2bf(y[15]) << 16);
  *(uint4*)(YT + qbase) = o0;
  *(uint4*)(YT + qbase + 8) = o1;
}

// -------------------------------------------------------------------------------
extern "C" void kernel_launch(void* const* d_in, const int* in_sizes, int n_in,
                              void* d_out, int out_size, void* d_ws, size_t ws_size,
                              hipStream_t stream) {
  const float* x  = (const float*)d_in[0];
  const float* wq = (const float*)d_in[1];
  const float* bq = (const float*)d_in[2];
  const float* wk = (const float*)d_in[3];
  const float* bk = (const float*)d_in[4];
  const float* wv = (const float*)d_in[5];
  const float* bv = (const float*)d_in[6];
  const float* wp = (const float*)d_in[7];
  const float* bp = (const float*)d_in[8];

  char* ws = (char*)d_ws;
  unsigned short* Wr = (unsigned short*)ws;       // 4*49152 bf16 = 393216 B
  float* biasf = (float*)(ws + 393216);           // 4*128 f32   = 2048 B
  size_t off = 395264;
  const size_t TENB = (size_t)NSLICE * S_SP * C_CH * 2;  // 67108864 B per tensor
  unsigned short* xT = (unsigned short*)(ws + off); off += TENB;
  unsigned short* QT = (unsigned short*)(ws + off); off += TENB;
  unsigned short* KT = (unsigned short*)(ws + off); off += TENB;
  unsigned short* VT = (unsigned short*)(ws + off); off += TENB;
  unsigned short* YT = xT;  // xT dead after QKV convs; reuse for attention out
  unsigned short* OT = QT;  // QT dead after attention; reuse for conv_p output

  // 1) repack weights / biases (fp32 -> bf16 / fp32)
  hipLaunchKernelGGL(repack_kernel, dim3(770), dim3(256), 0, stream,
                     wq, wk, wv, wp, bq, bk, bv, bp, Wr, biasf);
  // 2) x fp32 [c][s] -> xT bf16 [s][c]
  hipLaunchKernelGGL(transpose_f2b_kernel, dim3(256, 2, 16), dim3(256), 0, stream,
                     x, xT, 128, 16384);
  // 3) Q,K,V convs (z selects weights/output; Q,K,V contiguous in ws)
  hipLaunchKernelGGL(conv_mfma_kernel, dim3(128, 16, 3), dim3(256), 0, stream,
                     xT, Wr, biasf, QT);
  // 4) fused both-direction window attention -> YT
  hipLaunchKernelGGL(attn_kernel, dim3(1024, 8), dim3(256), 0, stream,
                     QT, KT, VT, YT);
  // 5) projection conv
  hipLaunchKernelGGL(conv_mfma_kernel, dim3(128, 16, 1), dim3(256), 0, stream,
                     YT, Wr + 3 * 49152, biasf + 384, OT);
  // 6) OT bf16 [s][o] -> d_out fp32 [o][s]
  hipLaunchKernelGGL(transpose_b2f_kernel, dim3(2, 256, 16), dim3(256), 0, stream,
                     OT, (float*)d_out, 16384, 128);
}

// Round 2
// 490.643 us; speedup vs baseline: 1.1447x; 1.0899x over previous
//
#include <hip/hip_runtime.h>

typedef __attribute__((ext_vector_type(8))) short short8;
typedef __attribute__((ext_vector_type(4))) float v4f;

#define C_CH 128
#define S_SP 16384
#define NSLICE 16
#define KTOT 384

__device__ inline float bf2f(unsigned short u) {
  union { unsigned int i; float f; } v; v.i = ((unsigned int)u) << 16; return v.f;
}
__device__ inline unsigned short f2bf(float f) {
  union { float f; unsigned int i; } v; v.f = f;
  unsigned int u = v.i;
  return (unsigned short)((u + 0x7FFFu + ((u >> 16) & 1u)) >> 16);
}

__device__ inline void gload_lds16(const unsigned short* g, unsigned short* l) {
  __builtin_amdgcn_global_load_lds(
      (const __attribute__((address_space(1))) void*)g,
      (__attribute__((address_space(3))) void*)l, 16, 0, 0);
}

// ---- weight repack: Wr[o][t*128+c] = bf16(w[o][c][t]); bias fp32 copy --------
__global__ __launch_bounds__(256) void repack_kernel(
    const float* __restrict__ wq, const float* __restrict__ wk,
    const float* __restrict__ wv, const float* __restrict__ wp,
    const float* __restrict__ bq, const float* __restrict__ bk,
    const float* __restrict__ bv, const float* __restrict__ bp,
    unsigned short* __restrict__ Wr, float* __restrict__ biasf)
{
  int i = blockIdx.x * 256 + threadIdx.x;
  const int WN = 4 * 49152;
  if (i < WN) {
    int m = i / 49152;
    int r = i % 49152;
    int o = r / 384, k = r % 384;
    int t = k >> 7, c = k & 127;
    const float* w = (m == 0) ? wq : (m == 1) ? wk : (m == 2) ? wv : wp;
    Wr[i] = f2bf(w[o * 384 + c * 3 + t]);
  } else if (i < WN + 512) {
    int j = i - WN;
    int m = j >> 7, o = j & 127;
    const float* bb = (m == 0) ? bq : (m == 1) ? bk : (m == 2) ? bv : bp;
    biasf[j] = bb[o];
  }
}

// ---- ingress: fp32 [R][C] -> bf16 [C][R], per z-slice (R=128, C=16384) -------
__global__ __launch_bounds__(256) void transpose_f2b_kernel(
    const float* __restrict__ in, unsigned short* __restrict__ out,
    int R, int C)
{
  __shared__ unsigned short t[64][72];
  int tid = threadIdx.x;
  size_t slice = blockIdx.z;
  const float* ip = in + slice * (size_t)R * C;
  unsigned short* op = out + slice * (size_t)R * C;
  int c0 = blockIdx.x * 64, r0 = blockIdx.y * 64;
#pragma unroll
  for (int p = 0; p < 4; ++p) {
    int id = tid + p * 256;
    int row = id >> 4, col = (id & 15) * 4;
    float4 v = *(const float4*)(ip + (size_t)(r0 + row) * C + c0 + col);
    t[row][col + 0] = f2bf(v.x);
    t[row][col + 1] = f2bf(v.y);
    t[row][col + 2] = f2bf(v.z);
    t[row][col + 3] = f2bf(v.w);
  }
  __syncthreads();
#pragma unroll
  for (int p = 0; p < 2; ++p) {
    int id = tid + p * 256;
    int crow = id >> 3, rcol = (id & 7) * 8;
    uint4 v;
    v.x = (unsigned)t[rcol + 0][crow] | ((unsigned)t[rcol + 1][crow] << 16);
    v.y = (unsigned)t[rcol + 2][crow] | ((unsigned)t[rcol + 3][crow] << 16);
    v.z = (unsigned)t[rcol + 4][crow] | ((unsigned)t[rcol + 5][crow] << 16);
    v.w = (unsigned)t[rcol + 6][crow] | ((unsigned)t[rcol + 7][crow] << 16);
    *(uint4*)(op + (size_t)(c0 + crow) * R + r0 + rcol) = v;
  }
}

// ---- egress: bf16 [R][C] -> fp32 [C][R], per z-slice (R=16384, C=128) --------
__global__ __launch_bounds__(256) void transpose_b2f_kernel(
    const unsigned short* __restrict__ in, float* __restrict__ out,
    int R, int C)
{
  __shared__ unsigned short t[64][72];
  int tid = threadIdx.x;
  size_t slice = blockIdx.z;
  const unsigned short* ip = in + slice * (size_t)R * C;
  float* op = out + slice * (size_t)R * C;
  int c0 = blockIdx.x * 64, r0 = blockIdx.y * 64;
#pragma unroll
  for (int p = 0; p < 2; ++p) {
    int id = tid + p * 256;
    int row = id >> 3, col = (id & 7) * 8;
    uint4 v = *(const uint4*)(ip + (size_t)(r0 + row) * C + c0 + col);
    *(uint4*)(&t[row][col]) = v;
  }
  __syncthreads();
#pragma unroll
  for (int p = 0; p < 4; ++p) {
    int id = tid + p * 256;
    int crow = id >> 4, rcol = (id & 15) * 4;
    float4 v;
    v.x = bf2f(t[rcol + 0][crow]);
    v.y = bf2f(t[rcol + 1][crow]);
    v.z = bf2f(t[rcol + 2][crow]);
    v.w = bf2f(t[rcol + 3][crow]);
    *(float4*)(op + (size_t)(c0 + crow) * R + r0 + rcol) = v;
  }
}

// ---- MFMA conv v3: per-phase A regs (3 rotating sets), tri-buffer B, ---------
// depth-2 counted-vmcnt pipeline (never drain to 0 in steady state).
// out[slice][s][o] = bias[o] + sum_k Wr[o,k]*Xc[s,k]
// Phases ap = t*2+sub (K=64 each), valid contiguous range [lo, hi].
// Per phase per wave: 8 loads = 4x gload_lds16 (B tile) + 4x short8 (A frags).
// At phase top: vmcnt(8) leaves next phase's group in flight; vmcnt(0) only at hi.
// Buffer p%3 overwritten at phase p+? : B(p+2) issued at p, consumed buf was
// drained by the barrier at p's top (all waves' ds_reads of p-1 complete).
__global__ __launch_bounds__(256, 3) void conv_mfma_kernel(
    const unsigned short* __restrict__ inT,
    const unsigned short* __restrict__ Wr_all,
    const float* __restrict__ bias_all,
    unsigned short* __restrict__ outT_all)
{
  __shared__ unsigned short Blds[3][128 * 64];  // 3 x 16 KB, linear (swizzled)

  int z = blockIdx.z;
  const unsigned short* Wr = Wr_all + (size_t)z * 49152;
  const float* bias = bias_all + z * 128;
  unsigned short* outT = outT_all + (size_t)z * NSLICE * S_SP * C_CH;

  int tid = threadIdx.x;
  int s0 = blockIdx.x * 128;
  int slice = blockIdx.y;
  int b = slice >> 3, l = slice & 7;
  int lh = l & 3;
  int t_lo = (lh == 0) ? 1 : 0;   // valid tap range keeps lp inside the half
  int t_hi = (lh == 3) ? 1 : 2;
  int lo = t_lo * 2, hi = t_hi * 2 + 1;   // contiguous valid phase range

  int w = tid >> 6, lane = tid & 63;
  int quad = lane >> 4, l15 = lane & 15;
  int srow_i = lane >> 3;                 // row within 8-row group
  int scs = (lane & 7) ^ srow_i;          // inverse-swizzled source chunk

  v4f acc[2][8];
#pragma unroll
  for (int i = 0; i < 2; ++i)
#pragma unroll
    for (int j = 0; j < 8; ++j)
      acc[i][j] = (v4f){0.f, 0.f, 0.f, 0.f};

  short8 af0[4], af1[4], af2[4];  // rotating per-phase A sets (static indexed)

#define STAGE(ap, bsel) do {                                                   \
    int t_ = (ap) >> 1;                                                        \
    const unsigned short* gb_ =                                                \
        inT + ((size_t)(b * 8 + l - 1 + t_) * S_SP + s0) * C_CH +              \
        ((ap) & 1) * 64;                                                       \
    _Pragma("unroll")                                                          \
    for (int q_ = 0; q_ < 4; ++q_)                                             \
      gload_lds16(gb_ + (size_t)((w * 4 + q_) * 8 + srow_i) * C_CH + scs * 8,  \
                  &Blds[bsel][(w * 4 + q_) * 512]);                            \
  } while (0)

#define AFLOAD(ap, set) do {                                                   \
    _Pragma("unroll")                                                          \
    for (int i_ = 0; i_ < 2; ++i_)                                             \
      _Pragma("unroll")                                                        \
      for (int ks_ = 0; ks_ < 2; ++ks_)                                        \
        set[i_ * 2 + ks_] = *(const short8*)(                                  \
            Wr + (size_t)(w * 32 + i_ * 16 + l15) * KTOT +                     \
            (ap) * 64 + ks_ * 32 + quad * 8);                                  \
  } while (0)

  // prologue: stage first two valid phases (group order pinned)
  if (lo == 0) {
    STAGE(0, 0); AFLOAD(0, af0);
    __builtin_amdgcn_sched_barrier(0);
    STAGE(1, 1); AFLOAD(1, af1);
  } else {
    STAGE(2, 2); AFLOAD(2, af2);
    __builtin_amdgcn_sched_barrier(0);
    STAGE(3, 0); AFLOAD(3, af0);
  }

#define PHASE(ap, CURSET, NXTSET)                                              \
  if ((ap) >= lo && (ap) <= hi) {                                              \
    if ((ap) == hi) { asm volatile("s_waitcnt vmcnt(0)" ::: "memory"); }       \
    else            { asm volatile("s_waitcnt vmcnt(8)" ::: "memory"); }       \
    __builtin_amdgcn_s_barrier();                                              \
    if ((ap) + 2 <= hi) { STAGE((ap) + 2, ((ap) + 2) % 3);                     \
                          AFLOAD((ap) + 2, NXTSET); }                          \
    const unsigned short* Bp_ = &Blds[(ap) % 3][0];                            \
    _Pragma("unroll")                                                          \
    for (int ks = 0; ks < 2; ++ks) {                                           \
      _Pragma("unroll")                                                        \
      for (int jg = 0; jg < 2; ++jg) {                                         \
        short8 bfr[4];                                                         \
        _Pragma("unroll")                                                      \
        for (int j4 = 0; j4 < 4; ++j4)                                         \
          bfr[j4] = *(const short8*)(                                          \
              Bp_ + ((jg * 4 + j4) * 16 + l15) * 64 +                          \
              (((ks * 4 + quad) ^ (l15 & 7)) * 8));                            \
        _Pragma("unroll")                                                      \
        for (int i = 0; i < 2; ++i)                                            \
          _Pragma("unroll")                                                    \
          for (int j4 = 0; j4 < 4; ++j4)                                       \
            acc[i][jg * 4 + j4] = __builtin_amdgcn_mfma_f32_16x16x32_bf16(     \
                CURSET[i * 2 + ks], bfr[j4], acc[i][jg * 4 + j4], 0, 0, 0);    \
      }                                                                        \
    }                                                                          \
  }

  PHASE(0, af0, af2)
  PHASE(1, af1, af0)
  PHASE(2, af2, af1)
  PHASE(3, af0, af2)
  PHASE(4, af1, af0)
  PHASE(5, af2, af0)

#undef PHASE
#undef AFLOAD
#undef STAGE

  // ---- epilogue: bias + bf16 pack + store -----------------------------------
#pragma unroll
  for (int i = 0; i < 2; ++i) {
    int obase = w * 32 + i * 16 + quad * 4;
    float4 bb = *(const float4*)(bias + obase);
#pragma unroll
    for (int j = 0; j < 8; ++j) {
      int s = s0 + j * 16 + l15;
      float f0 = acc[i][j].x + bb.x;
      float f1 = acc[i][j].y + bb.y;
      float f2 = acc[i][j].z + bb.z;
      float f3 = acc[i][j].w + bb.w;
      uint2 st;
      st.x = (unsigned)f2bf(f0) | ((unsigned)f2bf(f1) << 16);
      st.y = (unsigned)f2bf(f2) | ((unsigned)f2bf(f3) << 16);
      *(uint2*)(outT + ((size_t)slice * S_SP + s) * C_CH + obase) = st;
    }
  }
}

// ---- fused both-direction window attention -----------------------------------
__device__ inline void load16(const unsigned short* p, float* f) {
  uint4 a = *(const uint4*)p;
  uint4 c = *(const uint4*)(p + 8);
  unsigned v[8] = {a.x, a.y, a.z, a.w, c.x, c.y, c.z, c.w};
#pragma unroll
  for (int i = 0; i < 8; ++i) {
    f[2 * i] = bf2f((unsigned short)(v[i] & 0xffffu));
    f[2 * i + 1] = bf2f((unsigned short)(v[i] >> 16));
  }
}

__global__ __launch_bounds__(256) void attn_kernel(
    const unsigned short* __restrict__ QT,
    const unsigned short* __restrict__ KT,
    const unsigned short* __restrict__ VT,
    unsigned short* __restrict__ YT)
{
  int tid = threadIdx.x;
  int wave = tid >> 6, lane = tid & 63;
  int dir = wave & 1;
  int win = blockIdx.x * 2 + (wave >> 1);
  int by = blockIdx.y;
  int b = by >> 2, l0 = by & 3;
  int head = lane >> 3, qi = lane & 7;
  int d0 = win >> 8, h0 = (win >> 4) & 15, w0 = win & 15;
  int lq = l0 + dir * 4;
  int lk = l0 + 4 - dir * 4;
  int sE[8];
#pragma unroll
  for (int e = 0; e < 8; ++e)
    sE[e] = (2 * d0 + (e >> 2)) * 1024 + (2 * h0 + ((e >> 1) & 1)) * 32 + (2 * w0 + (e & 1));

  size_t qbase = ((size_t)(b * 8 + lq) * S_SP + sE[qi]) * C_CH + head * 16;
  size_t kslice = (size_t)(b * 8 + lk) * S_SP;
  float q[16];
  load16(QT + qbase, q);

  float lg[8];
#pragma unroll
  for (int j = 0; j < 8; ++j) {
    float kk[16];
    load16(KT + (kslice + sE[j]) * C_CH + head * 16, kk);
    float d = 0.f;
#pragma unroll
    for (int x = 0; x < 16; ++x) d += q[x] * kk[x];
    lg[j] = d * 0.25f;  // scale = (C/NH)^-0.5 = 1/4
  }
  float m = lg[0];
#pragma unroll
  for (int j = 1; j < 8; ++j) m = fmaxf(m, lg[j]);
  float p[8], sum = 0.f;
#pragma unroll
  for (int j = 0; j < 8; ++j) { p[j] = __expf(lg[j] - m); sum += p[j]; }
  float inv = 1.0f / sum;

  float y[16];
#pragma unroll
  for (int x = 0; x < 16; ++x) y[x] = 0.f;
#pragma unroll
  for (int j = 0; j < 8; ++j) {
    float vv[16];
    load16(VT + (kslice + sE[j]) * C_CH + head * 16, vv);
    float pj = p[j] * inv;
#pragma unroll
    for (int x = 0; x < 16; ++x) y[x] += pj * vv[x];
  }
  uint4 o0, o1;
  o0.x = (unsigned)f2bf(y[0]) | ((unsigned)f2bf(y[1]) << 16);
  o0.y = (unsigned)f2bf(y[2]) | ((unsigned)f2bf(y[3]) << 16);
  o0.z = (unsigned)f2bf(y[4]) | ((unsigned)f2bf(y[5]) << 16);
  o0.w = (unsigned)f2bf(y[6]) | ((unsigned)f2bf(y[7]) << 16);
  o1.x = (unsigned)f2bf(y[8]) | ((unsigned)f2bf(y[9]) << 16);
  o1.y = (unsigned)f2bf(y[10]) | ((unsigned)f2bf(y[11]) << 16);
  o1.z = (unsigned)f2bf(y[12]) | ((unsigned)f2bf(y[13]) << 16);
  o1.w = (unsigned)f2bf(y[14]) | ((unsigned)f2bf(y[15]) << 16);
  *(uint4*)(YT + qbase) = o0;
  *(uint4*)(YT + qbase + 8) = o1;
}

// -------------------------------------------------------------------------------
extern "C" void kernel_launch(void* const* d_in, const int* in_sizes, int n_in,
                              void* d_out, int out_size, void* d_ws, size_t ws_size,
                              hipStream_t stream) {
  const float* x  = (const float*)d_in[0];
  const float* wq = (const float*)d_in[1];
  const float* bq = (const float*)d_in[2];
  const float* wk = (const float*)d_in[3];
  const float* bk = (const float*)d_in[4];
  const float* wv = (const float*)d_in[5];
  const float* bv = (const float*)d_in[6];
  const float* wp = (const float*)d_in[7];
  const float* bp = (const float*)d_in[8];

  char* ws = (char*)d_ws;
  unsigned short* Wr = (unsigned short*)ws;       // 4*49152 bf16 = 393216 B
  float* biasf = (float*)(ws + 393216);           // 4*128 f32   = 2048 B
  size_t off = 395264;
  const size_t TENB = (size_t)NSLICE * S_SP * C_CH * 2;  // 67108864 B per tensor
  unsigned short* xT = (unsigned short*)(ws + off); off += TENB;
  unsigned short* QT = (unsigned short*)(ws + off); off += TENB;
  unsigned short* KT = (unsigned short*)(ws + off); off += TENB;
  unsigned short* VT = (unsigned short*)(ws + off); off += TENB;
  unsigned short* YT = xT;  // xT dead after QKV convs; reuse for attention out
  unsigned short* OT = QT;  // QT dead after attention; reuse for conv_p output

  // 1) repack weights / biases (fp32 -> bf16 / fp32)
  hipLaunchKernelGGL(repack_kernel, dim3(770), dim3(256), 0, stream,
                     wq, wk, wv, wp, bq, bk, bv, bp, Wr, biasf);
  // 2) x fp32 [c][s] -> xT bf16 [s][c]
  hipLaunchKernelGGL(transpose_f2b_kernel, dim3(256, 2, 16), dim3(256), 0, stream,
                     x, xT, 128, 16384);
  // 3) Q,K,V convs (z selects weights/output; Q,K,V contiguous in ws)
  hipLaunchKernelGGL(conv_mfma_kernel, dim3(128, 16, 3), dim3(256), 0, stream,
                     xT, Wr, biasf, QT);
  // 4) fused both-direction window attention -> YT
  hipLaunchKernelGGL(attn_kernel, dim3(1024, 8), dim3(256), 0, stream,
                     QT, KT, VT, YT);
  // 5) projection conv
  hipLaunchKernelGGL(conv_mfma_kernel, dim3(128, 16, 1), dim3(256), 0, stream,
                     YT, Wr + 3 * 49152, biasf + 384, OT);
  // 6) OT bf16 [s][o] -> d_out fp32 [o][s]
  hipLaunchKernelGGL(transpose_b2f_kernel, dim3(2, 256, 16), dim3(256), 0, stream,
                     OT, (float*)d_out, 16384, 128);
}